// Round 1
// baseline (5650.904 us; speedup 1.0000x reference)
//
#include <hip/hip_runtime.h>

#define NN 100000
#define BN_EPS 1e-5f

// ---------------- degree / normalization ----------------

__global__ __launch_bounds__(256) void k_init_deg(float* __restrict__ deg) {
    int i = blockIdx.x * 256 + threadIdx.x;
    if (i < NN) deg[i] = 1.0f;   // self-loop
}

__global__ __launch_bounds__(256) void k_count_deg(const int* __restrict__ col,
                                                   float* __restrict__ deg, int E) {
    int e = blockIdx.x * 256 + threadIdx.x;
    if (e < E) atomicAdd(&deg[col[e]], 1.0f);
}

__global__ __launch_bounds__(256) void k_rsqrt(float* __restrict__ d) {
    int i = blockIdx.x * 256 + threadIdx.x;
    if (i < NN) d[i] = rsqrtf(d[i]);
}

// ---------------- GEMM: out[N,128] = X[N,K] @ W[K,128], optional fused BN on X ----------------
// 32 nodes per block, 256 threads: thread -> (node-sub ns=t>>5, j-group jg=t&31, 4 outputs).
// W staged in LDS in K-tiles of 64 (32 KB), X tile (32*K) staged once with BN applied.

template<int K, bool BN>
__global__ __launch_bounds__(256) void k_gemm(const float* __restrict__ X,
                                              const float* __restrict__ W,
                                              const float* __restrict__ scale,
                                              const float* __restrict__ shift,
                                              float* __restrict__ out) {
    __shared__ __align__(16) float Ws[64 * 128];   // 32 KB
    __shared__ __align__(16) float Xs[32 * K];     // 8 or 16 KB
    const int t = threadIdx.x;
    const int base = blockIdx.x * 32;

    for (int i = t; i < 32 * K; i += 256) {
        float v = X[base * K + i];
        if constexpr (BN) { int k = i & (K - 1); v = v * scale[k] + shift[k]; }
        Xs[i] = v;
    }

    const int jg = t & 31;
    const int ns = t >> 5;
    float4 acc[4];
    #pragma unroll
    for (int p = 0; p < 4; ++p) acc[p] = make_float4(0.f, 0.f, 0.f, 0.f);

    for (int kt = 0; kt < K; kt += 64) {
        __syncthreads();   // previous Ws tile fully consumed (and Xs staged, iter 0)
        for (int i = t; i < 64 * 128; i += 256) Ws[i] = W[kt * 128 + i];
        __syncthreads();
        #pragma unroll
        for (int p = 0; p < 4; ++p) {
            const int n = p * 8 + ns;
            float4 a = acc[p];
            #pragma unroll 8
            for (int k2 = 0; k2 < 64; ++k2) {
                float xv = Xs[n * K + kt + k2];
                float4 wv = *reinterpret_cast<const float4*>(&Ws[k2 * 128 + jg * 4]);
                a.x = fmaf(xv, wv.x, a.x);
                a.y = fmaf(xv, wv.y, a.y);
                a.z = fmaf(xv, wv.z, a.z);
                a.w = fmaf(xv, wv.w, a.w);
            }
            acc[p] = a;
        }
    }
    #pragma unroll
    for (int p = 0; p < 4; ++p) {
        const int n = p * 8 + ns;
        *reinterpret_cast<float4*>(&out[(base + n) * 128 + jg * 4]) = acc[p];
    }
}

// ---------------- self-loop + bias init: out[n][j] = h[n][j]*dis[n]^2 + b[j] ----------------

__global__ __launch_bounds__(256) void k_selfloop(const float* __restrict__ h,
                                                  const float* __restrict__ dis,
                                                  const float* __restrict__ b,
                                                  float* __restrict__ out) {
    int i = blockIdx.x * 256 + threadIdx.x;       // float4 index, total NN*32
    if (i >= NN * 32) return;
    int n = i >> 5, p = i & 31;
    float d = dis[n];
    float c = d * d;
    float4 hv = reinterpret_cast<const float4*>(h)[i];
    float4 bv = reinterpret_cast<const float4*>(b)[p];
    float4 o;
    o.x = fmaf(hv.x, c, bv.x);
    o.y = fmaf(hv.y, c, bv.y);
    o.z = fmaf(hv.z, c, bv.z);
    o.w = fmaf(hv.w, c, bv.w);
    reinterpret_cast<float4*>(out)[i] = o;
}

// ---------------- edge aggregation: agg[col] += h[row] * dis[row]*dis[col] ----------------
// 32 threads per edge, each handles 4 consecutive features (float4 gather, 4 scalar atomics).

__global__ __launch_bounds__(256) void k_edge_agg(const int* __restrict__ row,
                                                  const int* __restrict__ col,
                                                  const float* __restrict__ dis,
                                                  const float* __restrict__ h,
                                                  float* __restrict__ agg, int E) {
    int e = blockIdx.x * 8 + (threadIdx.x >> 5);
    if (e >= E) return;
    int p = threadIdx.x & 31;
    int r = row[e], c = col[e];
    float coef = dis[r] * dis[c];
    float4 v = reinterpret_cast<const float4*>(h)[r * 32 + p];
    float* dst = agg + c * 128 + p * 4;
    atomicAdd(dst + 0, v.x * coef);
    atomicAdd(dst + 1, v.y * coef);
    atomicAdd(dst + 2, v.z * coef);
    atomicAdd(dst + 3, v.w * coef);
}

// ---------------- batchnorm stats (two-stage: per-block partials + atomics) ----------------

__global__ __launch_bounds__(128) void k_bn_stats(const float* __restrict__ x,
                                                  float* __restrict__ sums,
                                                  float* __restrict__ sumsq) {
    const int j = threadIdx.x;            // feature 0..127
    const int r0 = blockIdx.x * 128;
    const int rend = min(r0 + 128, NN);
    float s = 0.f, s2 = 0.f;
    for (int r = r0; r < rend; ++r) {
        float v = x[r * 128 + j];
        s += v;
        s2 += v * v;
    }
    atomicAdd(&sums[j], s);
    atomicAdd(&sumsq[j], s2);
}

__global__ __launch_bounds__(128) void k_bn_finalize(const float* __restrict__ sums,
                                                     const float* __restrict__ sumsq,
                                                     const float* __restrict__ gamma,
                                                     const float* __restrict__ beta,
                                                     float* __restrict__ scale,
                                                     float* __restrict__ shift) {
    int j = threadIdx.x;
    const float n = (float)NN;
    float mean = sums[j] / n;
    float var = sumsq[j] / n - mean * mean;
    float sc = gamma[j] * rsqrtf(var + BN_EPS);
    scale[j] = sc;
    shift[j] = beta[j] - mean * sc;
}

// ---------------- launch ----------------

extern "C" void kernel_launch(void* const* d_in, const int* in_sizes, int n_in,
                              void* d_out, int out_size, void* d_ws, size_t ws_size,
                              hipStream_t stream) {
    const float* x     = (const float*)d_in[0];   // [NN, 64]
    const int*   ei    = (const int*)d_in[1];     // [2, E]
    const float* W1    = (const float*)d_in[2];   // [64, 128]
    const float* b1    = (const float*)d_in[3];   // [128]
    const float* gamma = (const float*)d_in[4];   // [128]
    const float* beta  = (const float*)d_in[5];   // [128]
    const float* W2    = (const float*)d_in[6];   // [128, 128]
    const float* b2    = (const float*)d_in[7];   // [128]
    float* out = (float*)d_out;                   // [NN, 128]

    const int E = in_sizes[1] / 2;
    const int* row = ei;
    const int* col = ei + E;

    // workspace layout (floats)
    float* dis   = (float*)d_ws;            // NN floats (also deg)
    float* sums  = dis + 102400;            // 128
    float* sumsq = sums + 128;              // 128
    float* scale = sumsq + 128;             // 128
    float* shift = scale + 128;             // 128
    float* hbuf  = dis + 102912;            // NN*128 floats (16B aligned offset)

    const int gN = (NN + 255) / 256;

    // 1. normalization coefficients
    k_init_deg<<<gN, 256, 0, stream>>>(dis);
    k_count_deg<<<(E + 255) / 256, 256, 0, stream>>>(col, dis, E);
    k_rsqrt<<<gN, 256, 0, stream>>>(dis);

    // 2. layer 1: h1 = x @ W1
    k_gemm<64, false><<<NN / 32, 256, 0, stream>>>(x, W1, nullptr, nullptr, hbuf);

    // 3. agg1 -> d_out (self-loop + bias init, then edge atomics)
    k_selfloop<<<(NN * 32 + 255) / 256, 256, 0, stream>>>(hbuf, dis, b1, out);
    k_edge_agg<<<(E + 7) / 8, 256, 0, stream>>>(row, col, dis, hbuf, out, E);

    // 4. batchnorm stats over d_out
    hipMemsetAsync(sums, 0, 2 * 128 * sizeof(float), stream);
    k_bn_stats<<<(NN + 127) / 128, 128, 0, stream>>>(out, sums, sumsq);
    k_bn_finalize<<<1, 128, 0, stream>>>(sums, sumsq, gamma, beta, scale, shift);

    // 5. layer 2: h2 = BN(out) @ W2  (BN fused into X staging)
    k_gemm<128, true><<<NN / 32, 256, 0, stream>>>(out, W2, scale, shift, hbuf);

    // 6. agg2 -> d_out
    k_selfloop<<<(NN * 32 + 255) / 256, 256, 0, stream>>>(hbuf, dis, b2, out);
    k_edge_agg<<<(E + 7) / 8, 256, 0, stream>>>(row, col, dis, hbuf, out, E);
}

// Round 2
// 571.436 us; speedup vs baseline: 9.8890x; 9.8890x over previous
//
#include <hip/hip_runtime.h>

#define NN 100000
#define BN_EPS 1e-5f
#define SCAN_B 256
#define NBLK ((NN + SCAN_B - 1) / SCAN_B)   // 391

// ---------------- CSR build ----------------

__global__ __launch_bounds__(256) void k_hist(const int* __restrict__ col,
                                              int* __restrict__ cnt, int E) {
    int e = blockIdx.x * 256 + threadIdx.x;
    if (e < E) atomicAdd(&cnt[col[e]], 1);
}

__global__ __launch_bounds__(SCAN_B) void k_scan_block(const int* __restrict__ cnt,
                                                       int* __restrict__ start,
                                                       int* __restrict__ bsum) {
    __shared__ int s[SCAN_B];
    const int t = threadIdx.x;
    const int i = blockIdx.x * SCAN_B + t;
    int v = (i < NN) ? cnt[i] : 0;
    s[t] = v;
    __syncthreads();
    #pragma unroll
    for (int off = 1; off < SCAN_B; off <<= 1) {
        int add = (t >= off) ? s[t - off] : 0;
        __syncthreads();
        s[t] += add;
        __syncthreads();
    }
    if (i < NN) start[i] = s[t] - v;            // exclusive (block-local)
    if (t == SCAN_B - 1) bsum[blockIdx.x] = s[t];
}

__global__ __launch_bounds__(512) void k_scan_top(const int* __restrict__ bsum,
                                                  int* __restrict__ boff) {
    __shared__ int s[512];
    const int t = threadIdx.x;
    int v = (t < NBLK) ? bsum[t] : 0;
    s[t] = v;
    __syncthreads();
    #pragma unroll
    for (int off = 1; off < 512; off <<= 1) {
        int add = (t >= off) ? s[t - off] : 0;
        __syncthreads();
        s[t] += add;
        __syncthreads();
    }
    if (t < NBLK) boff[t] = s[t] - v;           // exclusive
}

__global__ __launch_bounds__(256) void k_scan_add(int* __restrict__ start,
                                                  const int* __restrict__ boff,
                                                  int* __restrict__ cursor,
                                                  const int* __restrict__ cnt,
                                                  float* __restrict__ dis) {
    int i = blockIdx.x * 256 + threadIdx.x;
    if (i >= NN) return;
    int sv = start[i] + boff[i / SCAN_B];
    start[i] = sv;
    cursor[i] = sv;
    dis[i] = rsqrtf((float)(cnt[i] + 1));       // deg = in-edges + self-loop
}

__global__ __launch_bounds__(256) void k_scatter(const int* __restrict__ row,
                                                 const int* __restrict__ col,
                                                 int* __restrict__ cursor,
                                                 int* __restrict__ rows, int E) {
    int e = blockIdx.x * 256 + threadIdx.x;
    if (e >= E) return;
    int pos = atomicAdd(&cursor[col[e]], 1);
    rows[pos] = row[e];
}

// ---------------- pull aggregation: agg[n] = dis[n]^2*x[n] + sum_e coef*x[row_e] ----------------
// F features; F/4 lanes per node (float4 each). SUMC: also emit sumcoef[n] = (D~ 1)[n].

template<int F, bool SUMC>
__global__ __launch_bounds__(256) void k_agg(const float* __restrict__ x,
                                             const int* __restrict__ rows,
                                             const int* __restrict__ start,
                                             const int* __restrict__ cnt,
                                             const float* __restrict__ dis,
                                             float* __restrict__ agg,
                                             float* __restrict__ sumcoef) {
    constexpr int L = F / 4;                    // lanes per node
    const int t = threadIdx.x;
    const int g = t / L;
    const int fid = t % L;
    const int n = blockIdx.x * (256 / L) + g;
    if (n >= NN) return;
    const int s = start[n];
    const int c = cnt[n];
    const float dn = dis[n];
    float4 acc = reinterpret_cast<const float4*>(x)[n * L + fid];
    const float dn2 = dn * dn;
    acc.x *= dn2; acc.y *= dn2; acc.z *= dn2; acc.w *= dn2;
    float sd = 0.f;
    for (int k = 0; k < c; ++k) {
        int r = rows[s + k];
        float dr = dis[r];
        float coef = dr * dn;
        float4 v = reinterpret_cast<const float4*>(x)[r * L + fid];
        acc.x = fmaf(v.x, coef, acc.x);
        acc.y = fmaf(v.y, coef, acc.y);
        acc.z = fmaf(v.z, coef, acc.z);
        acc.w = fmaf(v.w, coef, acc.w);
        sd += dr;
    }
    reinterpret_cast<float4*>(agg)[n * L + fid] = acc;
    if (SUMC && fid == 0) sumcoef[n] = dn * sd + dn2;
}

// ---------------- GEMM: out[N,128] = X[N,K] @ W[K,128] + bias ----------------
// BNA: staged X element -> X*scale[k] + shift[k]*sumcoef[n]  (fused BN-after-agg algebra)

template<int K, bool BNA>
__global__ __launch_bounds__(256) void k_gemm(const float* __restrict__ X,
                                              const float* __restrict__ W,
                                              const float* __restrict__ bias,
                                              const float* __restrict__ scale,
                                              const float* __restrict__ shift,
                                              const float* __restrict__ sumcoef,
                                              float* __restrict__ out) {
    __shared__ __align__(16) float Ws[64 * 128];
    __shared__ __align__(16) float Xs[32 * K];
    const int t = threadIdx.x;
    const int base = blockIdx.x * 32;

    for (int i = t; i < 32 * K; i += 256) {
        float v = X[base * K + i];
        if constexpr (BNA) {
            int k = i & (K - 1);
            int n = i / K;
            v = v * scale[k] + shift[k] * sumcoef[base + n];
        }
        Xs[i] = v;
    }

    const int jg = t & 31;
    const int ns = t >> 5;
    float4 acc[4];
    #pragma unroll
    for (int p = 0; p < 4; ++p) acc[p] = make_float4(0.f, 0.f, 0.f, 0.f);

    for (int kt = 0; kt < K; kt += 64) {
        __syncthreads();
        for (int i = t; i < 64 * 128; i += 256) Ws[i] = W[kt * 128 + i];
        __syncthreads();
        #pragma unroll
        for (int p = 0; p < 4; ++p) {
            const int n = p * 8 + ns;
            float4 a = acc[p];
            #pragma unroll 8
            for (int k2 = 0; k2 < 64; ++k2) {
                float xv = Xs[n * K + kt + k2];
                float4 wv = *reinterpret_cast<const float4*>(&Ws[k2 * 128 + jg * 4]);
                a.x = fmaf(xv, wv.x, a.x);
                a.y = fmaf(xv, wv.y, a.y);
                a.z = fmaf(xv, wv.z, a.z);
                a.w = fmaf(xv, wv.w, a.w);
            }
            acc[p] = a;
        }
    }
    const float4 bv = *reinterpret_cast<const float4*>(&bias[jg * 4]);
    #pragma unroll
    for (int p = 0; p < 4; ++p) {
        const int n = p * 8 + ns;
        float4 a = acc[p];
        a.x += bv.x; a.y += bv.y; a.z += bv.z; a.w += bv.w;
        *reinterpret_cast<float4*>(&out[(base + n) * 128 + jg * 4]) = a;
    }
}

// ---------------- batchnorm stats ----------------

__global__ __launch_bounds__(128) void k_bn_stats(const float* __restrict__ x,
                                                  float* __restrict__ sums,
                                                  float* __restrict__ sumsq) {
    const int j = threadIdx.x;
    const int r0 = blockIdx.x * 128;
    const int rend = min(r0 + 128, NN);
    float s = 0.f, s2 = 0.f;
    for (int r = r0; r < rend; ++r) {
        float v = x[r * 128 + j];
        s += v;
        s2 += v * v;
    }
    atomicAdd(&sums[j], s);
    atomicAdd(&sumsq[j], s2);
}

__global__ __launch_bounds__(128) void k_bn_finalize(const float* __restrict__ sums,
                                                     const float* __restrict__ sumsq,
                                                     const float* __restrict__ gamma,
                                                     const float* __restrict__ beta,
                                                     float* __restrict__ scale,
                                                     float* __restrict__ shift) {
    int j = threadIdx.x;
    const float n = (float)NN;
    float mean = sums[j] / n;
    float var = sumsq[j] / n - mean * mean;
    float sc = gamma[j] * rsqrtf(var + BN_EPS);
    scale[j] = sc;
    shift[j] = beta[j] - mean * sc;
}

// ---------------- launch ----------------

extern "C" void kernel_launch(void* const* d_in, const int* in_sizes, int n_in,
                              void* d_out, int out_size, void* d_ws, size_t ws_size,
                              hipStream_t stream) {
    const float* x     = (const float*)d_in[0];   // [NN, 64]
    const int*   ei    = (const int*)d_in[1];     // [2, E]
    const float* W1    = (const float*)d_in[2];
    const float* b1    = (const float*)d_in[3];
    const float* gamma = (const float*)d_in[4];
    const float* beta  = (const float*)d_in[5];
    const float* W2    = (const float*)d_in[6];
    const float* b2    = (const float*)d_in[7];
    float* out = (float*)d_out;                   // [NN, 128]

    const int E = in_sizes[1] / 2;
    const int* row = ei;
    const int* col = ei + E;

    // workspace layout (all offsets in 4-byte units, NN rounded to 102400)
    int*   cnt     = (int*)d_ws;            // NN
    int*   start   = cnt + 102400;          // NN
    int*   cursor  = start + 102400;        // NN
    int*   bsum    = cursor + 102400;       // 512
    int*   boff    = bsum + 512;            // 512
    float* dis     = (float*)(boff + 512);  // NN
    float* sums    = dis + 102400;          // 128
    float* sumsq   = sums + 128;            // 128
    float* scale   = sumsq + 128;           // 128
    float* shift   = scale + 128;           // 128
    float* sumcoef = shift + 128;           // NN (pad to 102400 below)
    int*   rows    = (int*)(sumcoef + 102400);           // E
    float* h1      = (float*)(rows + ((E + 511) & ~511)); // NN*128
    // total ~ 2.5 MB aux + 6.4 MB rows + 51.2 MB h1 ~= 60 MB

    const int gN = (NN + 255) / 256;        // 391
    const int gE = (E + 255) / 256;

    // 1. CSR build + normalization
    hipMemsetAsync(cnt, 0, NN * sizeof(int), stream);
    k_hist<<<gE, 256, 0, stream>>>(col, cnt, E);
    k_scan_block<<<NBLK, SCAN_B, 0, stream>>>(cnt, start, bsum);
    k_scan_top<<<1, 512, 0, stream>>>(bsum, boff);
    k_scan_add<<<gN, 256, 0, stream>>>(start, boff, cursor, cnt, dis);
    k_scatter<<<gE, 256, 0, stream>>>(row, col, cursor, rows, E);

    // 2. layer 1: aggregate x (64 feats) -> d_out scratch, then GEMM -> h1
    k_agg<64, false><<<NN / 16, 256, 0, stream>>>(x, rows, start, cnt, dis,
                                                  out, nullptr);
    k_gemm<64, false><<<NN / 32, 256, 0, stream>>>(out, W1, b1, nullptr, nullptr,
                                                   nullptr, h1);

    // 3. BN stats on h1
    hipMemsetAsync(sums, 0, 2 * 128 * sizeof(float), stream);
    k_bn_stats<<<(NN + 127) / 128, 128, 0, stream>>>(h1, sums, sumsq);
    k_bn_finalize<<<1, 128, 0, stream>>>(sums, sumsq, gamma, beta, scale, shift);

    // 4. layer 2: aggregate raw h1 (+ sumcoef), BN folded into GEMM staging, in-place in d_out
    k_agg<128, true><<<NN / 8, 256, 0, stream>>>(h1, rows, start, cnt, dis,
                                                 out, sumcoef);
    k_gemm<128, true><<<NN / 32, 256, 0, stream>>>(out, W2, b2, scale, shift,
                                                   sumcoef, out);
}

// Round 3
// 491.364 us; speedup vs baseline: 11.5004x; 1.1630x over previous
//
#include <hip/hip_runtime.h>

#define NN 100000
#define BN_EPS 1e-5f
#define SCAN_B 256
#define NBLK ((NN + SCAN_B - 1) / SCAN_B)   // 391

typedef __attribute__((ext_vector_type(4))) _Float16 half4;

// ---------------- CSR build ----------------

__global__ __launch_bounds__(256) void k_hist4(const int* __restrict__ col,
                                               int* __restrict__ cnt, int EQ, int E) {
    int i = blockIdx.x * 256 + threadIdx.x;
    if (i < EQ) {
        int4 c4 = reinterpret_cast<const int4*>(col)[i];
        atomicAdd(&cnt[c4.x], 1);
        atomicAdd(&cnt[c4.y], 1);
        atomicAdd(&cnt[c4.z], 1);
        atomicAdd(&cnt[c4.w], 1);
    }
    int tail0 = EQ * 4;
    if (i < E - tail0) atomicAdd(&cnt[col[tail0 + i]], 1);
}

__global__ __launch_bounds__(256) void k_hist1(const int* __restrict__ col,
                                               int* __restrict__ cnt, int E) {
    int e = blockIdx.x * 256 + threadIdx.x;
    if (e < E) atomicAdd(&cnt[col[e]], 1);
}

__global__ __launch_bounds__(SCAN_B) void k_scan_block(const int* __restrict__ cnt,
                                                       int* __restrict__ start,
                                                       int* __restrict__ bsum) {
    __shared__ int s[SCAN_B];
    const int t = threadIdx.x;
    const int i = blockIdx.x * SCAN_B + t;
    int v = (i < NN) ? cnt[i] : 0;
    s[t] = v;
    __syncthreads();
    #pragma unroll
    for (int off = 1; off < SCAN_B; off <<= 1) {
        int add = (t >= off) ? s[t - off] : 0;
        __syncthreads();
        s[t] += add;
        __syncthreads();
    }
    if (i < NN) start[i] = s[t] - v;            // exclusive (block-local)
    if (t == SCAN_B - 1) bsum[blockIdx.x] = s[t];
}

__global__ __launch_bounds__(512) void k_scan_top(const int* __restrict__ bsum,
                                                  int* __restrict__ boff) {
    __shared__ int s[512];
    const int t = threadIdx.x;
    int v = (t < NBLK) ? bsum[t] : 0;
    s[t] = v;
    __syncthreads();
    #pragma unroll
    for (int off = 1; off < 512; off <<= 1) {
        int add = (t >= off) ? s[t - off] : 0;
        __syncthreads();
        s[t] += add;
        __syncthreads();
    }
    if (t < NBLK) boff[t] = s[t] - v;           // exclusive
}

__global__ __launch_bounds__(256) void k_scan_add(int* __restrict__ start,
                                                  const int* __restrict__ boff,
                                                  int* __restrict__ cursor,
                                                  const int* __restrict__ cnt,
                                                  float* __restrict__ dis) {
    int i = blockIdx.x * 256 + threadIdx.x;
    if (i >= NN) return;
    int sv = start[i] + boff[i / SCAN_B];
    start[i] = sv;
    cursor[i] = sv;
    dis[i] = rsqrtf((float)(cnt[i] + 1));       // deg = in-edges + self-loop
}

__global__ __launch_bounds__(256) void k_scatter4(const int* __restrict__ row,
                                                  const int* __restrict__ col,
                                                  int* __restrict__ cursor,
                                                  int* __restrict__ rows, int EQ, int E) {
    int i = blockIdx.x * 256 + threadIdx.x;
    if (i < EQ) {
        int4 c4 = reinterpret_cast<const int4*>(col)[i];
        int4 r4 = reinterpret_cast<const int4*>(row)[i];
        int p0 = atomicAdd(&cursor[c4.x], 1);
        int p1 = atomicAdd(&cursor[c4.y], 1);
        int p2 = atomicAdd(&cursor[c4.z], 1);
        int p3 = atomicAdd(&cursor[c4.w], 1);
        rows[p0] = r4.x;
        rows[p1] = r4.y;
        rows[p2] = r4.z;
        rows[p3] = r4.w;
    }
    int tail0 = EQ * 4;
    if (i < E - tail0) {
        int e = tail0 + i;
        int pos = atomicAdd(&cursor[col[e]], 1);
        rows[pos] = row[e];
    }
}

__global__ __launch_bounds__(256) void k_scatter1(const int* __restrict__ row,
                                                  const int* __restrict__ col,
                                                  int* __restrict__ cursor,
                                                  int* __restrict__ rows, int E) {
    int e = blockIdx.x * 256 + threadIdx.x;
    if (e >= E) return;
    int pos = atomicAdd(&cursor[col[e]], 1);
    rows[pos] = row[e];
}

// ---------------- x (f32) -> f16 copy ----------------

__global__ __launch_bounds__(256) void k_cvt(const float* __restrict__ x,
                                             _Float16* __restrict__ xh, int n4) {
    int i = blockIdx.x * 256 + threadIdx.x;
    if (i >= n4) return;
    float4 v = reinterpret_cast<const float4*>(x)[i];
    half4 o;
    o.x = (_Float16)v.x; o.y = (_Float16)v.y; o.z = (_Float16)v.z; o.w = (_Float16)v.w;
    reinterpret_cast<half4*>(xh)[i] = o;
}

// ---------------- pull aggregation (f16 gather -> f32 accumulate) ----------------
// agg[n] = dis[n]^2*x[n] + sum_e dis[r]*dis[n]*x[r];  SUMC: sumcoef[n] = dn*(sum dr) + dn^2

__device__ __forceinline__ void fma_h4(float4& a, half4 v, float c) {
    a.x = fmaf((float)v.x, c, a.x);
    a.y = fmaf((float)v.y, c, a.y);
    a.z = fmaf((float)v.z, c, a.z);
    a.w = fmaf((float)v.w, c, a.w);
}

template<int F, bool SUMC>
__global__ __launch_bounds__(256) void k_agg(const _Float16* __restrict__ xh,
                                             const int* __restrict__ rows,
                                             const int* __restrict__ start,
                                             const int* __restrict__ cnt,
                                             const float* __restrict__ dis,
                                             float* __restrict__ agg,
                                             float* __restrict__ sumcoef) {
    constexpr int L = F / 4;                    // lanes per node (half4 each)
    const int t = threadIdx.x;
    const int g = t / L;
    const int fid = t % L;
    const int n = blockIdx.x * (256 / L) + g;
    if (n >= NN) return;
    const int s = start[n];
    const int c = cnt[n];
    const float dn = dis[n];
    const half4* X4 = reinterpret_cast<const half4*>(xh);
    half4 hv = X4[n * L + fid];
    const float dn2 = dn * dn;
    float4 acc = make_float4(dn2 * (float)hv.x, dn2 * (float)hv.y,
                             dn2 * (float)hv.z, dn2 * (float)hv.w);
    float sd = 0.f;
    const int* rp = rows + s;
    int k = 0;
    for (; k + 4 <= c; k += 4) {
        int r0 = rp[k], r1 = rp[k + 1], r2 = rp[k + 2], r3 = rp[k + 3];
        float d0 = dis[r0], d1 = dis[r1], d2 = dis[r2], d3 = dis[r3];
        half4 v0 = X4[r0 * L + fid];
        half4 v1 = X4[r1 * L + fid];
        half4 v2 = X4[r2 * L + fid];
        half4 v3 = X4[r3 * L + fid];
        fma_h4(acc, v0, d0 * dn);
        fma_h4(acc, v1, d1 * dn);
        fma_h4(acc, v2, d2 * dn);
        fma_h4(acc, v3, d3 * dn);
        sd += (d0 + d1) + (d2 + d3);
    }
    for (; k < c; ++k) {
        int r = rp[k];
        float dr = dis[r];
        half4 v = X4[r * L + fid];
        fma_h4(acc, v, dr * dn);
        sd += dr;
    }
    reinterpret_cast<float4*>(agg)[n * L + fid] = acc;
    if (SUMC && fid == 0) sumcoef[n] = dn * sd + dn2;
}

// ---------------- GEMM: out[N,128] = X[N,K] @ W[K,128] + bias ----------------
// BNA: staged X element -> X*scale[k] + shift[k]*sumcoef[n]; OUT16: write f16

template<int K, bool BNA, bool OUT16>
__global__ __launch_bounds__(256) void k_gemm(const float* __restrict__ X,
                                              const float* __restrict__ W,
                                              const float* __restrict__ bias,
                                              const float* __restrict__ scale,
                                              const float* __restrict__ shift,
                                              const float* __restrict__ sumcoef,
                                              float* __restrict__ out,
                                              _Float16* __restrict__ out16) {
    __shared__ __align__(16) float Ws[64 * 128];
    __shared__ __align__(16) float Xs[32 * K];
    const int t = threadIdx.x;
    const int base = blockIdx.x * 32;

    for (int i = t; i < 32 * K; i += 256) {
        float v = X[base * K + i];
        if constexpr (BNA) {
            int k = i & (K - 1);
            int n = i / K;
            v = v * scale[k] + shift[k] * sumcoef[base + n];
        }
        Xs[i] = v;
    }

    const int jg = t & 31;
    const int ns = t >> 5;
    float4 acc[4];
    #pragma unroll
    for (int p = 0; p < 4; ++p) acc[p] = make_float4(0.f, 0.f, 0.f, 0.f);

    for (int kt = 0; kt < K; kt += 64) {
        __syncthreads();
        for (int i = t; i < 64 * 128; i += 256) Ws[i] = W[kt * 128 + i];
        __syncthreads();
        #pragma unroll
        for (int p = 0; p < 4; ++p) {
            const int n = p * 8 + ns;
            float4 a = acc[p];
            #pragma unroll 8
            for (int k2 = 0; k2 < 64; ++k2) {
                float xv = Xs[n * K + kt + k2];
                float4 wv = *reinterpret_cast<const float4*>(&Ws[k2 * 128 + jg * 4]);
                a.x = fmaf(xv, wv.x, a.x);
                a.y = fmaf(xv, wv.y, a.y);
                a.z = fmaf(xv, wv.z, a.z);
                a.w = fmaf(xv, wv.w, a.w);
            }
            acc[p] = a;
        }
    }
    const float4 bv = *reinterpret_cast<const float4*>(&bias[jg * 4]);
    #pragma unroll
    for (int p = 0; p < 4; ++p) {
        const int n = p * 8 + ns;
        float4 a = acc[p];
        a.x += bv.x; a.y += bv.y; a.z += bv.z; a.w += bv.w;
        if constexpr (OUT16) {
            half4 o;
            o.x = (_Float16)a.x; o.y = (_Float16)a.y;
            o.z = (_Float16)a.z; o.w = (_Float16)a.w;
            reinterpret_cast<half4*>(&out16[(base + n) * 128 + jg * 4])[0] = o;
        } else {
            *reinterpret_cast<float4*>(&out[(base + n) * 128 + jg * 4]) = a;
        }
    }
}

// ---------------- batchnorm stats over f16 h1 ----------------

__global__ __launch_bounds__(128) void k_bn_stats(const _Float16* __restrict__ x,
                                                  float* __restrict__ sums,
                                                  float* __restrict__ sumsq) {
    const int j = threadIdx.x;
    const int r0 = blockIdx.x * 128;
    const int rend = min(r0 + 128, NN);
    float s = 0.f, s2 = 0.f;
    for (int r = r0; r < rend; ++r) {
        float v = (float)x[r * 128 + j];
        s += v;
        s2 += v * v;
    }
    atomicAdd(&sums[j], s);
    atomicAdd(&sumsq[j], s2);
}

__global__ __launch_bounds__(128) void k_bn_finalize(const float* __restrict__ sums,
                                                     const float* __restrict__ sumsq,
                                                     const float* __restrict__ gamma,
                                                     const float* __restrict__ beta,
                                                     float* __restrict__ scale,
                                                     float* __restrict__ shift) {
    int j = threadIdx.x;
    const float n = (float)NN;
    float mean = sums[j] / n;
    float var = sumsq[j] / n - mean * mean;
    float sc = gamma[j] * rsqrtf(var + BN_EPS);
    scale[j] = sc;
    shift[j] = beta[j] - mean * sc;
}

// ---------------- launch ----------------

extern "C" void kernel_launch(void* const* d_in, const int* in_sizes, int n_in,
                              void* d_out, int out_size, void* d_ws, size_t ws_size,
                              hipStream_t stream) {
    const float* x     = (const float*)d_in[0];   // [NN, 64]
    const int*   ei    = (const int*)d_in[1];     // [2, E]
    const float* W1    = (const float*)d_in[2];
    const float* b1    = (const float*)d_in[3];
    const float* gamma = (const float*)d_in[4];
    const float* beta  = (const float*)d_in[5];
    const float* W2    = (const float*)d_in[6];
    const float* b2    = (const float*)d_in[7];
    float* out = (float*)d_out;                   // [NN, 128]

    const int E = in_sizes[1] / 2;
    const int* row = ei;
    const int* col = ei + E;

    // workspace layout (4-byte units; NN padded to 102400)
    int*   cnt     = (int*)d_ws;            // 102400
    int*   start   = cnt + 102400;
    int*   cursor  = start + 102400;
    int*   bsum    = cursor + 102400;       // 512
    int*   boff    = bsum + 512;            // 512
    float* dis     = (float*)(boff + 512);  // 102400
    float* sums    = dis + 102400;          // 128
    float* sumsq   = sums + 128;
    float* scale   = sumsq + 128;
    float* shift   = scale + 128;
    float* sumcoef = shift + 128;           // 102400
    int*   rows    = (int*)(sumcoef + 102400);                 // E (padded)
    _Float16* xh   = (_Float16*)(rows + ((E + 511) & ~511));   // NN*64 halves
    _Float16* h1   = xh + 102400 * 64;                         // NN*128 halves

    const int gN = (NN + 255) / 256;        // 391
    const int EQ = E / 4;

    // 1. CSR build + normalization (+ x -> f16 before anything needs it)
    hipMemsetAsync(cnt, 0, NN * sizeof(int), stream);
    k_cvt<<<(NN * 16 + 255) / 256, 256, 0, stream>>>(x, xh, NN * 16);
    if ((E & 3) == 0) {
        k_hist4<<<(EQ + 255) / 256, 256, 0, stream>>>(col, cnt, EQ, E);
    } else {
        k_hist1<<<(E + 255) / 256, 256, 0, stream>>>(col, cnt, E);
    }
    k_scan_block<<<NBLK, SCAN_B, 0, stream>>>(cnt, start, bsum);
    k_scan_top<<<1, 512, 0, stream>>>(bsum, boff);
    k_scan_add<<<gN, 256, 0, stream>>>(start, boff, cursor, cnt, dis);
    if ((E & 3) == 0) {
        k_scatter4<<<(EQ + 255) / 256, 256, 0, stream>>>(row, col, cursor, rows, EQ, E);
    } else {
        k_scatter1<<<(E + 255) / 256, 256, 0, stream>>>(row, col, cursor, rows, E);
    }

    // 2. layer 1: aggregate xh (64 feats) -> d_out scratch (f32), GEMM -> h1 (f16)
    k_agg<64, false><<<NN / 16, 256, 0, stream>>>(xh, rows, start, cnt, dis,
                                                  out, nullptr);
    k_gemm<64, false, true><<<NN / 32, 256, 0, stream>>>(out, W1, b1, nullptr, nullptr,
                                                         nullptr, nullptr, h1);

    // 3. BN stats on f16 h1
    hipMemsetAsync(sums, 0, 2 * 128 * sizeof(float), stream);
    k_bn_stats<<<(NN + 127) / 128, 128, 0, stream>>>(h1, sums, sumsq);
    k_bn_finalize<<<1, 128, 0, stream>>>(sums, sumsq, gamma, beta, scale, shift);

    // 4. layer 2: aggregate f16 h1 (+ sumcoef), BN folded into GEMM staging, in-place
    k_agg<128, true><<<NN / 8, 256, 0, stream>>>(h1, rows, start, cnt, dis,
                                                 out, sumcoef);
    k_gemm<128, true, false><<<NN / 32, 256, 0, stream>>>(out, W2, b2, scale, shift,
                                                          sumcoef, out, nullptr);
}

// Round 4
// 326.375 us; speedup vs baseline: 17.3141x; 1.5055x over previous
//
#include <hip/hip_runtime.h>

#define NN 100000
#define BN_EPS 1e-5f
#define NB 391          // buckets = ceil(NN/256), bucket b owns cols [b*256, b*256+256)
#define CAP 5120        // per-bucket edge capacity (lambda=4096, +16 sigma)
#define TILE 4096       // edges per k_bin block

typedef __attribute__((ext_vector_type(4))) _Float16 half4;

// ---------------- pass 1: bin edges by col>>8, bucket-sorted coalesced writes ----------------

__global__ __launch_bounds__(256) void k_bin(const int* __restrict__ row,
                                             const int* __restrict__ col,
                                             int* __restrict__ bcur,   // NB counters, stride 16
                                             int* __restrict__ ebuf,   // NB*CAP packed edges
                                             int E) {
    __shared__ int hist[512];
    __shared__ int excl[512];
    __shared__ int cur[512];
    __shared__ int gbase[512];
    __shared__ int sc[256];
    __shared__ int staged[TILE];
    __shared__ unsigned short bkt[TILE];
    const int t = threadIdx.x;
    const int base = blockIdx.x * TILE;
    const int nE = min(TILE, E - base);

    hist[t] = 0; hist[t + 256] = 0;
    cur[t] = 0;  cur[t + 256] = 0;
    __syncthreads();

    // load up to 16 edges/thread into regs (coalesced), build bucket histogram
    int er[16], ec[16];
    #pragma unroll
    for (int k = 0; k < 16; ++k) {
        int idx = base + k * 256 + t;
        if (idx < E) {
            er[k] = row[idx];
            ec[k] = col[idx];
            atomicAdd(&hist[ec[k] >> 8], 1);
        } else {
            ec[k] = -1;
        }
    }
    __syncthreads();

    // exclusive scan of hist[512] with 256 threads (pair-sum + Hillis-Steele)
    int p = hist[2 * t] + hist[2 * t + 1];
    sc[t] = p;
    __syncthreads();
    for (int off = 1; off < 256; off <<= 1) {
        int add = (t >= off) ? sc[t - off] : 0;
        __syncthreads();
        sc[t] += add;
        __syncthreads();
    }
    int P = sc[t];                       // inclusive pair-sum scan
    excl[2 * t]     = P - p;
    excl[2 * t + 1] = P - p + hist[2 * t];
    __syncthreads();

    // reserve global space per bucket (padded counters: 1 per 64B line)
    for (int b = t; b < NB; b += 256) {
        int h = hist[b];
        gbase[b] = h ? atomicAdd(&bcur[b * 16], h) : 0;
    }

    // stage edges bucket-sorted in LDS
    #pragma unroll
    for (int k = 0; k < 16; ++k) {
        int c = ec[k];
        if (c < 0) continue;
        int b = c >> 8;
        int slot = excl[b] + atomicAdd(&cur[b], 1);
        staged[slot] = (er[k] << 8) | (c & 255);
        bkt[slot] = (unsigned short)b;
    }
    __syncthreads();

    // coalesced write: consecutive slots in a bucket -> consecutive global addrs
    for (int i = t; i < nE; i += 256) {
        int b = bkt[i];
        int off = gbase[b] + (i - excl[b]);
        if (off < CAP) ebuf[b * CAP + off] = staged[i];
    }
}

// ---------------- pass 2: per-bucket CSR finalize (deg, dis, start, rows) ----------------

__global__ __launch_bounds__(256) void k_csr(const int* __restrict__ bcur,
                                             const int* __restrict__ ebuf,
                                             int* __restrict__ rows,
                                             int* __restrict__ start,
                                             int* __restrict__ cnt,
                                             float* __restrict__ dis) {
    __shared__ int hist[256];
    __shared__ int lstart[256];
    __shared__ int cur[256];
    __shared__ int sc[256];
    const int b = blockIdx.x;
    const int t = threadIdx.x;
    const int fill = min(bcur[b * 16], CAP);

    hist[t] = 0; cur[t] = 0;
    __syncthreads();

    int er[CAP / 256];                   // 20 regs max
    #pragma unroll
    for (int k = 0; k < CAP / 256; ++k) {
        int i = k * 256 + t;
        if (i < fill) {
            er[k] = ebuf[b * CAP + i];
            atomicAdd(&hist[er[k] & 255], 1);
        }
    }
    __syncthreads();

    // exclusive scan of hist[256]
    int v = hist[t];
    sc[t] = v;
    __syncthreads();
    for (int off = 1; off < 256; off <<= 1) {
        int add = (t >= off) ? sc[t - off] : 0;
        __syncthreads();
        sc[t] += add;
        __syncthreads();
    }
    lstart[t] = sc[t] - v;

    const int node = b * 256 + t;
    if (node < NN) {
        start[node] = b * CAP + lstart[t];   // careful: lstart[t] == sc[t]-v, valid now
        cnt[node] = v;
        dis[node] = rsqrtf((float)(v + 1));
    }
    __syncthreads();

    // scatter rows into this bucket's small window (L2-resident)
    #pragma unroll
    for (int k = 0; k < CAP / 256; ++k) {
        int i = k * 256 + t;
        if (i < fill) {
            int lc = er[k] & 255;
            int lpos = atomicAdd(&cur[lc], 1);
            rows[b * CAP + lstart[lc] + lpos] = er[k] >> 8;
        }
    }
}

// ---------------- x (f32) -> f16 copy ----------------

__global__ __launch_bounds__(256) void k_cvt(const float* __restrict__ x,
                                             _Float16* __restrict__ xh, int n4) {
    int i = blockIdx.x * 256 + threadIdx.x;
    if (i >= n4) return;
    float4 v = reinterpret_cast<const float4*>(x)[i];
    half4 o;
    o.x = (_Float16)v.x; o.y = (_Float16)v.y; o.z = (_Float16)v.z; o.w = (_Float16)v.w;
    reinterpret_cast<half4*>(xh)[i] = o;
}

// ---------------- pull aggregation (f16 gather -> f32 accumulate) ----------------

__device__ __forceinline__ void fma_h4(float4& a, half4 v, float c) {
    a.x = fmaf((float)v.x, c, a.x);
    a.y = fmaf((float)v.y, c, a.y);
    a.z = fmaf((float)v.z, c, a.z);
    a.w = fmaf((float)v.w, c, a.w);
}

template<int F, bool SUMC>
__global__ __launch_bounds__(256) void k_agg(const _Float16* __restrict__ xh,
                                             const int* __restrict__ rows,
                                             const int* __restrict__ start,
                                             const int* __restrict__ cnt,
                                             const float* __restrict__ dis,
                                             float* __restrict__ agg,
                                             float* __restrict__ sumcoef) {
    constexpr int L = F / 4;
    const int t = threadIdx.x;
    const int g = t / L;
    const int fid = t % L;
    const int n = blockIdx.x * (256 / L) + g;
    if (n >= NN) return;
    const int s = start[n];
    const int c = cnt[n];
    const float dn = dis[n];
    const half4* X4 = reinterpret_cast<const half4*>(xh);
    half4 hv = X4[n * L + fid];
    const float dn2 = dn * dn;
    float4 acc = make_float4(dn2 * (float)hv.x, dn2 * (float)hv.y,
                             dn2 * (float)hv.z, dn2 * (float)hv.w);
    float sd = 0.f;
    const int* rp = rows + s;
    int k = 0;
    for (; k + 4 <= c; k += 4) {
        int r0 = rp[k], r1 = rp[k + 1], r2 = rp[k + 2], r3 = rp[k + 3];
        float d0 = dis[r0], d1 = dis[r1], d2 = dis[r2], d3 = dis[r3];
        half4 v0 = X4[r0 * L + fid];
        half4 v1 = X4[r1 * L + fid];
        half4 v2 = X4[r2 * L + fid];
        half4 v3 = X4[r3 * L + fid];
        fma_h4(acc, v0, d0 * dn);
        fma_h4(acc, v1, d1 * dn);
        fma_h4(acc, v2, d2 * dn);
        fma_h4(acc, v3, d3 * dn);
        sd += (d0 + d1) + (d2 + d3);
    }
    for (; k < c; ++k) {
        int r = rp[k];
        float dr = dis[r];
        half4 v = X4[r * L + fid];
        fma_h4(acc, v, dr * dn);
        sd += dr;
    }
    reinterpret_cast<float4*>(agg)[n * L + fid] = acc;
    if (SUMC && fid == 0) sumcoef[n] = dn * sd + dn2;
}

// ---------------- GEMM: out[N,128] = X[N,K] @ W[K,128] + bias ----------------

template<int K, bool BNA, bool OUT16>
__global__ __launch_bounds__(256) void k_gemm(const float* __restrict__ X,
                                              const float* __restrict__ W,
                                              const float* __restrict__ bias,
                                              const float* __restrict__ scale,
                                              const float* __restrict__ shift,
                                              const float* __restrict__ sumcoef,
                                              float* __restrict__ out,
                                              _Float16* __restrict__ out16) {
    __shared__ __align__(16) float Ws[64 * 128];
    __shared__ __align__(16) float Xs[32 * K];
    const int t = threadIdx.x;
    const int base = blockIdx.x * 32;

    for (int i = t; i < 32 * K; i += 256) {
        float v = X[base * K + i];
        if constexpr (BNA) {
            int k = i & (K - 1);
            int n = i / K;
            v = v * scale[k] + shift[k] * sumcoef[base + n];
        }
        Xs[i] = v;
    }

    const int jg = t & 31;
    const int ns = t >> 5;
    float4 acc[4];
    #pragma unroll
    for (int p = 0; p < 4; ++p) acc[p] = make_float4(0.f, 0.f, 0.f, 0.f);

    for (int kt = 0; kt < K; kt += 64) {
        __syncthreads();
        for (int i = t; i < 64 * 128; i += 256) Ws[i] = W[kt * 128 + i];
        __syncthreads();
        #pragma unroll
        for (int p = 0; p < 4; ++p) {
            const int n = p * 8 + ns;
            float4 a = acc[p];
            #pragma unroll 8
            for (int k2 = 0; k2 < 64; ++k2) {
                float xv = Xs[n * K + kt + k2];
                float4 wv = *reinterpret_cast<const float4*>(&Ws[k2 * 128 + jg * 4]);
                a.x = fmaf(xv, wv.x, a.x);
                a.y = fmaf(xv, wv.y, a.y);
                a.z = fmaf(xv, wv.z, a.z);
                a.w = fmaf(xv, wv.w, a.w);
            }
            acc[p] = a;
        }
    }
    const float4 bv = *reinterpret_cast<const float4*>(&bias[jg * 4]);
    #pragma unroll
    for (int p = 0; p < 4; ++p) {
        const int n = p * 8 + ns;
        float4 a = acc[p];
        a.x += bv.x; a.y += bv.y; a.z += bv.z; a.w += bv.w;
        if constexpr (OUT16) {
            half4 o;
            o.x = (_Float16)a.x; o.y = (_Float16)a.y;
            o.z = (_Float16)a.z; o.w = (_Float16)a.w;
            reinterpret_cast<half4*>(&out16[(base + n) * 128 + jg * 4])[0] = o;
        } else {
            *reinterpret_cast<float4*>(&out[(base + n) * 128 + jg * 4]) = a;
        }
    }
}

// ---------------- batchnorm stats over f16 h1 ----------------

__global__ __launch_bounds__(128) void k_bn_stats(const _Float16* __restrict__ x,
                                                  float* __restrict__ sums,
                                                  float* __restrict__ sumsq) {
    const int j = threadIdx.x;
    const int r0 = blockIdx.x * 128;
    const int rend = min(r0 + 128, NN);
    float s = 0.f, s2 = 0.f;
    for (int r = r0; r < rend; ++r) {
        float v = (float)x[r * 128 + j];
        s += v;
        s2 += v * v;
    }
    atomicAdd(&sums[j], s);
    atomicAdd(&sumsq[j], s2);
}

__global__ __launch_bounds__(128) void k_bn_finalize(const float* __restrict__ sums,
                                                     const float* __restrict__ sumsq,
                                                     const float* __restrict__ gamma,
                                                     const float* __restrict__ beta,
                                                     float* __restrict__ scale,
                                                     float* __restrict__ shift) {
    int j = threadIdx.x;
    const float n = (float)NN;
    float mean = sums[j] / n;
    float var = sumsq[j] / n - mean * mean;
    float sc = gamma[j] * rsqrtf(var + BN_EPS);
    scale[j] = sc;
    shift[j] = beta[j] - mean * sc;
}

// ---------------- launch ----------------

extern "C" void kernel_launch(void* const* d_in, const int* in_sizes, int n_in,
                              void* d_out, int out_size, void* d_ws, size_t ws_size,
                              hipStream_t stream) {
    const float* x     = (const float*)d_in[0];   // [NN, 64]
    const int*   ei    = (const int*)d_in[1];     // [2, E]
    const float* W1    = (const float*)d_in[2];
    const float* b1    = (const float*)d_in[3];
    const float* gamma = (const float*)d_in[4];
    const float* beta  = (const float*)d_in[5];
    const float* W2    = (const float*)d_in[6];
    const float* b2    = (const float*)d_in[7];
    float* out = (float*)d_out;                   // [NN, 128]

    const int E = in_sizes[1] / 2;
    const int* row = ei;
    const int* col = ei + E;

    // workspace layout (4-byte units)
    int*   bcur    = (int*)d_ws;                      // NB*16 padded counters (8192)
    int*   cnt     = bcur + 8192;                     // 102400
    int*   start   = cnt + 102400;                    // 102400
    float* dis     = (float*)(start + 102400);        // 102400
    float* sums    = dis + 102400;                    // 128
    float* sumsq   = sums + 128;
    float* scale   = sumsq + 128;
    float* shift   = scale + 128;
    float* sumcoef = shift + 128;                     // 102400
    int*   ebuf    = (int*)(sumcoef + 102400);        // NB*CAP = 2,001,920
    int*   rows    = ebuf + NB * CAP;                 // NB*CAP
    _Float16* xh   = (_Float16*)(rows + NB * CAP);    // NN*64 halves (pad 102400)
    _Float16* h1   = xh + 102400 * 64;                // NN*128 halves

    // 1. CSR build via bucket sort + x -> f16
    hipMemsetAsync(bcur, 0, 8192 * sizeof(int), stream);
    hipMemsetAsync(sums, 0, 2 * 128 * sizeof(float), stream);
    k_cvt<<<(NN * 16 + 255) / 256, 256, 0, stream>>>(x, xh, NN * 16);
    k_bin<<<(E + TILE - 1) / TILE, 256, 0, stream>>>(row, col, bcur, ebuf, E);
    k_csr<<<NB, 256, 0, stream>>>(bcur, ebuf, rows, start, cnt, dis);

    // 2. layer 1: aggregate xh (64 feats) -> d_out scratch (f32), GEMM -> h1 (f16)
    k_agg<64, false><<<NN / 16, 256, 0, stream>>>(xh, rows, start, cnt, dis,
                                                  out, nullptr);
    k_gemm<64, false, true><<<NN / 32, 256, 0, stream>>>(out, W1, b1, nullptr, nullptr,
                                                         nullptr, nullptr, h1);

    // 3. BN stats on f16 h1
    k_bn_stats<<<(NN + 127) / 128, 128, 0, stream>>>(h1, sums, sumsq);
    k_bn_finalize<<<1, 128, 0, stream>>>(sums, sumsq, gamma, beta, scale, shift);

    // 4. layer 2: aggregate f16 h1 (+ sumcoef), BN folded into GEMM staging, in-place
    k_agg<128, true><<<NN / 8, 256, 0, stream>>>(h1, rows, start, cnt, dis,
                                                 out, sumcoef);
    k_gemm<128, true, false><<<NN / 32, 256, 0, stream>>>(out, W2, b2, scale, shift,
                                                          sumcoef, out, nullptr);
}

// Round 5
// 239.774 us; speedup vs baseline: 23.5677x; 1.3612x over previous
//
#include <hip/hip_runtime.h>

#define NN 100000
#define BN_EPS 1e-5f
#define NB 391          // buckets = ceil(NN/256), bucket b owns cols [b*256, b*256+256)
#define CAP 5120        // per-bucket edge capacity
#define TILE 4096       // edges per k_bin block

typedef __attribute__((ext_vector_type(4))) _Float16 half4;
typedef __attribute__((ext_vector_type(8))) _Float16 half8;
typedef __attribute__((ext_vector_type(4))) float f32x4;

// ---------------- pass 1: bin edges by col>>8, bucket-sorted coalesced writes ----------------

__global__ __launch_bounds__(256) void k_bin(const int* __restrict__ row,
                                             const int* __restrict__ col,
                                             int* __restrict__ bcur,   // NB counters, stride 16
                                             int* __restrict__ ebuf,   // NB*CAP packed edges
                                             int E) {
    __shared__ int hist[512];
    __shared__ int excl[512];
    __shared__ int cur[512];
    __shared__ int gbase[512];
    __shared__ int sc[256];
    __shared__ int staged[TILE];
    __shared__ unsigned short bkt[TILE];
    const int t = threadIdx.x;
    const int base = blockIdx.x * TILE;
    const int nE = min(TILE, E - base);

    hist[t] = 0; hist[t + 256] = 0;
    cur[t] = 0;  cur[t + 256] = 0;
    __syncthreads();

    int er[16], ec[16];
    #pragma unroll
    for (int k = 0; k < 16; ++k) {
        int idx = base + k * 256 + t;
        if (idx < E) {
            er[k] = row[idx];
            ec[k] = col[idx];
            atomicAdd(&hist[ec[k] >> 8], 1);
        } else {
            ec[k] = -1;
        }
    }
    __syncthreads();

    int p = hist[2 * t] + hist[2 * t + 1];
    sc[t] = p;
    __syncthreads();
    for (int off = 1; off < 256; off <<= 1) {
        int add = (t >= off) ? sc[t - off] : 0;
        __syncthreads();
        sc[t] += add;
        __syncthreads();
    }
    int P = sc[t];
    excl[2 * t]     = P - p;
    excl[2 * t + 1] = P - p + hist[2 * t];
    __syncthreads();

    for (int b = t; b < NB; b += 256) {
        int h = hist[b];
        gbase[b] = h ? atomicAdd(&bcur[b * 16], h) : 0;
    }

    #pragma unroll
    for (int k = 0; k < 16; ++k) {
        int c = ec[k];
        if (c < 0) continue;
        int b = c >> 8;
        int slot = excl[b] + atomicAdd(&cur[b], 1);
        staged[slot] = (er[k] << 8) | (c & 255);
        bkt[slot] = (unsigned short)b;
    }
    __syncthreads();

    for (int i = t; i < nE; i += 256) {
        int b = bkt[i];
        int off = gbase[b] + (i - excl[b]);
        if (off < CAP) ebuf[b * CAP + off] = staged[i];
    }
}

// ---------------- pass 2: per-bucket CSR finalize ----------------

__global__ __launch_bounds__(256) void k_csr(const int* __restrict__ bcur,
                                             const int* __restrict__ ebuf,
                                             int* __restrict__ rows,
                                             int* __restrict__ start,
                                             int* __restrict__ cnt,
                                             float* __restrict__ dis) {
    __shared__ int hist[256];
    __shared__ int lstart[256];
    __shared__ int cur[256];
    __shared__ int sc[256];
    const int b = blockIdx.x;
    const int t = threadIdx.x;
    const int fill = min(bcur[b * 16], CAP);

    hist[t] = 0; cur[t] = 0;
    __syncthreads();

    int er[CAP / 256];
    #pragma unroll
    for (int k = 0; k < CAP / 256; ++k) {
        int i = k * 256 + t;
        if (i < fill) {
            er[k] = ebuf[b * CAP + i];
            atomicAdd(&hist[er[k] & 255], 1);
        }
    }
    __syncthreads();

    int v = hist[t];
    sc[t] = v;
    __syncthreads();
    for (int off = 1; off < 256; off <<= 1) {
        int add = (t >= off) ? sc[t - off] : 0;
        __syncthreads();
        sc[t] += add;
        __syncthreads();
    }
    lstart[t] = sc[t] - v;

    const int node = b * 256 + t;
    if (node < NN) {
        start[node] = b * CAP + lstart[t];
        cnt[node] = v;
        dis[node] = rsqrtf((float)(v + 1));
    }
    __syncthreads();

    #pragma unroll
    for (int k = 0; k < CAP / 256; ++k) {
        int i = k * 256 + t;
        if (i < fill) {
            int lc = er[k] & 255;
            int lpos = atomicAdd(&cur[lc], 1);
            rows[b * CAP + lstart[lc] + lpos] = er[k] >> 8;
        }
    }
}

// ---------------- x (f32) -> f16 copy ----------------

__global__ __launch_bounds__(256) void k_cvt(const float* __restrict__ x,
                                             _Float16* __restrict__ xh, int n4) {
    int i = blockIdx.x * 256 + threadIdx.x;
    if (i >= n4) return;
    float4 v = reinterpret_cast<const float4*>(x)[i];
    half4 o;
    o.x = (_Float16)v.x; o.y = (_Float16)v.y; o.z = (_Float16)v.z; o.w = (_Float16)v.w;
    reinterpret_cast<half4*>(xh)[i] = o;
}

// ---------------- pull aggregation (f16 gather -> f32 accumulate -> f16 out) ----------------

__device__ __forceinline__ void fma_h4(float4& a, half4 v, float c) {
    a.x = fmaf((float)v.x, c, a.x);
    a.y = fmaf((float)v.y, c, a.y);
    a.z = fmaf((float)v.z, c, a.z);
    a.w = fmaf((float)v.w, c, a.w);
}

template<int F, bool SUMC>
__global__ __launch_bounds__(256) void k_agg(const _Float16* __restrict__ xh,
                                             const int* __restrict__ rows,
                                             const int* __restrict__ start,
                                             const int* __restrict__ cnt,
                                             const float* __restrict__ dis,
                                             _Float16* __restrict__ agg,
                                             float* __restrict__ sumcoef) {
    constexpr int L = F / 4;
    const int t = threadIdx.x;
    const int g = t / L;
    const int fid = t % L;
    const int n = blockIdx.x * (256 / L) + g;
    if (n >= NN) return;
    const int s = start[n];
    const int c = cnt[n];
    const float dn = dis[n];
    const half4* X4 = reinterpret_cast<const half4*>(xh);
    half4 hv = X4[n * L + fid];
    const float dn2 = dn * dn;
    float4 acc = make_float4(dn2 * (float)hv.x, dn2 * (float)hv.y,
                             dn2 * (float)hv.z, dn2 * (float)hv.w);
    float sd = 0.f;
    const int* rp = rows + s;
    int k = 0;
    for (; k + 4 <= c; k += 4) {
        int r0 = rp[k], r1 = rp[k + 1], r2 = rp[k + 2], r3 = rp[k + 3];
        float d0 = dis[r0], d1 = dis[r1], d2 = dis[r2], d3 = dis[r3];
        half4 v0 = X4[r0 * L + fid];
        half4 v1 = X4[r1 * L + fid];
        half4 v2 = X4[r2 * L + fid];
        half4 v3 = X4[r3 * L + fid];
        fma_h4(acc, v0, d0 * dn);
        fma_h4(acc, v1, d1 * dn);
        fma_h4(acc, v2, d2 * dn);
        fma_h4(acc, v3, d3 * dn);
        sd += (d0 + d1) + (d2 + d3);
    }
    for (; k < c; ++k) {
        int r = rp[k];
        float dr = dis[r];
        half4 v = X4[r * L + fid];
        fma_h4(acc, v, dr * dn);
        sd += dr;
    }
    half4 o;
    o.x = (_Float16)acc.x; o.y = (_Float16)acc.y;
    o.z = (_Float16)acc.z; o.w = (_Float16)acc.w;
    reinterpret_cast<half4*>(agg)[n * L + fid] = o;
    if (SUMC && fid == 0) sumcoef[n] = dn * sd + dn2;
}

// ---------------- W pack into MFMA B-fragment order ----------------
// wp flat idx i = ((kt*8 + nt)*64 + l)*8 + j  ->  W[kt*32 + (l>>4)*8 + j][nt*16 + (l&15)]

template<bool SC>
__global__ __launch_bounds__(256) void k_pack(const float* __restrict__ W,
                                              const float* __restrict__ scale,
                                              _Float16* __restrict__ wp, int KW) {
    int i = blockIdx.x * 256 + threadIdx.x;
    if (i >= KW * 128) return;
    int j = i & 7, l = (i >> 3) & 63, nt = (i >> 9) & 7, kt = i >> 12;
    int k = kt * 32 + ((l >> 4) << 3) + j;
    int n = nt * 16 + (l & 15);
    float v = W[k * 128 + n];
    if (SC) v *= scale[k];
    wp[i] = (_Float16)v;
}

// sv[j] = sum_k shift[k] * W2[k][j]
__global__ __launch_bounds__(128) void k_sv(const float* __restrict__ W2,
                                            const float* __restrict__ shift,
                                            float* __restrict__ sv) {
    int j = threadIdx.x;
    float s = 0.f;
    for (int k = 0; k < 128; ++k) s += shift[k] * W2[k * 128 + j];
    sv[j] = s;
}

// ---------------- MFMA GEMM: [NN,K] f16 @ packed W -> 128 cols ----------------
// Block = 256 thr = 4 waves; wave computes 16 rows x 128 cols (8 16x16 frags).
// L2E=false: out16 = acc + bias (f16), fused BN stats atomics.
// L2E=true:  out32 = acc + sumcoef[row]*sv[n] + bias[n] (f32, final output).

template<int K, bool L2E>
__global__ __launch_bounds__(256) void k_mgemm(const _Float16* __restrict__ A,
                                               const _Float16* __restrict__ Wp,
                                               const float* __restrict__ bias,
                                               const float* __restrict__ sv,
                                               const float* __restrict__ sumcoef,
                                               _Float16* __restrict__ out16,
                                               float* __restrict__ out32,
                                               float* __restrict__ sums,
                                               float* __restrict__ sumsq) {
    const int t = threadIdx.x;
    const int wv = t >> 6;
    const int ln = t & 63;
    const int cgrp = ln >> 4;            // 0..3 (k-chunk for A/B, row-group for D)
    const int ncol = ln & 15;
    const int r0 = blockIdx.x * 64 + wv * 16;
    const int arow = min(r0 + ncol, NN - 1);   // A fragment row = ln&15

    f32x4 acc[8];
    #pragma unroll
    for (int nt = 0; nt < 8; ++nt) acc[nt] = {0.f, 0.f, 0.f, 0.f};

    const half8* Ap = reinterpret_cast<const half8*>(A + arow * K + cgrp * 8);
    const half8* Bp = reinterpret_cast<const half8*>(Wp);

    #pragma unroll
    for (int kt = 0; kt < K / 32; ++kt) {
        half8 a = Ap[kt * 4];            // advance 32 halves = 4 half8
        #pragma unroll
        for (int nt = 0; nt < 8; ++nt) {
            half8 b = Bp[(kt * 8 + nt) * 64 + ln];
            acc[nt] = __builtin_amdgcn_mfma_f32_16x16x32_f16(a, b, acc[nt], 0, 0, 0);
        }
    }

    if constexpr (!L2E) {
        __shared__ float ls[4][128];
        __shared__ float ls2[4][128];
        #pragma unroll
        for (int nt = 0; nt < 8; ++nt) {
            const int n = nt * 16 + ncol;
            const float bn = bias[n];
            float s = 0.f, s2 = 0.f;
            #pragma unroll
            for (int j = 0; j < 4; ++j) {
                int gr = r0 + cgrp * 4 + j;
                float v = acc[nt][j] + bn;
                if (gr < NN) {
                    out16[gr * 128 + n] = (_Float16)v;
                    s += v;
                    s2 += v * v;
                }
            }
            s  += __shfl_xor(s, 16);  s  += __shfl_xor(s, 32);
            s2 += __shfl_xor(s2, 16); s2 += __shfl_xor(s2, 32);
            if (ln < 16) { ls[wv][n] = s; ls2[wv][n] = s2; }
        }
        __syncthreads();
        if (t < 128) {
            atomicAdd(&sums[t], ls[0][t] + ls[1][t] + ls[2][t] + ls[3][t]);
        } else {
            int u = t - 128;
            atomicAdd(&sumsq[u], ls2[0][u] + ls2[1][u] + ls2[2][u] + ls2[3][u]);
        }
    } else {
        float scj[4];
        #pragma unroll
        for (int j = 0; j < 4; ++j) scj[j] = sumcoef[min(r0 + cgrp * 4 + j, NN - 1)];
        #pragma unroll
        for (int nt = 0; nt < 8; ++nt) {
            const int n = nt * 16 + ncol;
            const float svn = sv[n];
            const float bn = bias[n];
            #pragma unroll
            for (int j = 0; j < 4; ++j) {
                int gr = r0 + cgrp * 4 + j;
                if (gr < NN) out32[gr * 128 + n] = acc[nt][j] + scj[j] * svn + bn;
            }
        }
    }
}

// ---------------- BN finalize ----------------

__global__ __launch_bounds__(128) void k_bn_finalize(const float* __restrict__ sums,
                                                     const float* __restrict__ sumsq,
                                                     const float* __restrict__ gamma,
                                                     const float* __restrict__ beta,
                                                     float* __restrict__ scale,
                                                     float* __restrict__ shift) {
    int j = threadIdx.x;
    const float n = (float)NN;
    float mean = sums[j] / n;
    float var = sumsq[j] / n - mean * mean;
    float sc = gamma[j] * rsqrtf(var + BN_EPS);
    scale[j] = sc;
    shift[j] = beta[j] - mean * sc;
}

// ---------------- launch ----------------

extern "C" void kernel_launch(void* const* d_in, const int* in_sizes, int n_in,
                              void* d_out, int out_size, void* d_ws, size_t ws_size,
                              hipStream_t stream) {
    const float* x     = (const float*)d_in[0];   // [NN, 64]
    const int*   ei    = (const int*)d_in[1];     // [2, E]
    const float* W1    = (const float*)d_in[2];
    const float* b1    = (const float*)d_in[3];
    const float* gamma = (const float*)d_in[4];
    const float* beta  = (const float*)d_in[5];
    const float* W2    = (const float*)d_in[6];
    const float* b2    = (const float*)d_in[7];
    float* out = (float*)d_out;                   // [NN, 128]

    const int E = in_sizes[1] / 2;
    const int* row = ei;
    const int* col = ei + E;

    // workspace layout (4-byte units)
    int*   bcur    = (int*)d_ws;                      // 8192
    int*   cnt     = bcur + 8192;                     // 102400
    int*   start   = cnt + 102400;                    // 102400
    float* dis     = (float*)(start + 102400);        // 102400
    float* sums    = dis + 102400;                    // 128
    float* sumsq   = sums + 128;                      // 128
    float* scale   = sumsq + 128;                     // 128
    float* shift   = scale + 128;                     // 128
    float* sv      = shift + 128;                     // 128 (region padded to 1024)
    float* sumcoef = sums + 1024;                     // 102400
    _Float16* wp1  = (_Float16*)(sumcoef + 102400);   // 8192 halves (4096 ints)
    _Float16* wp2  = wp1 + 8192;                      // 16384 halves (8192 ints)
    int*   rows    = (int*)(wp2 + 16384);             // NB*CAP = 2,001,920
    int*   Rbase   = rows + NB * CAP;                 // reuse region: 6,400,000 ints
    _Float16* xh   = (_Float16*)Rbase;                //   pass A: NN*64 f16 (3.2M ints)
    int*   ebuf    = Rbase + 3276800;                 //   pass A: NB*CAP ints (8MB)
    _Float16* aggB = (_Float16*)Rbase;                //   pass B: NN*128 f16 (25.6MB)
    _Float16* h1   = (_Float16*)(Rbase + 6400000);    // NN*128 f16 (25.6MB)
    _Float16* aggA = (_Float16*)d_out;                // NN*64 f16 parked in d_out (dead region)

    // 1. CSR build via bucket sort + x -> f16 + W1 pack + zero stats
    hipMemsetAsync(bcur, 0, 8192 * sizeof(int), stream);
    hipMemsetAsync(sums, 0, 2 * 128 * sizeof(float), stream);
    k_cvt<<<(NN * 16 + 255) / 256, 256, 0, stream>>>(x, xh, NN * 16);
    k_bin<<<(E + TILE - 1) / TILE, 256, 0, stream>>>(row, col, bcur, ebuf, E);
    k_csr<<<NB, 256, 0, stream>>>(bcur, ebuf, rows, start, cnt, dis);
    k_pack<false><<<32, 256, 0, stream>>>(W1, nullptr, wp1, 64);

    // 2. layer 1: aggregate xh (64) -> aggA f16, MFMA GEMM -> h1 f16 (+ fused BN stats)
    k_agg<64, false><<<NN / 16, 256, 0, stream>>>(xh, rows, start, cnt, dis,
                                                  aggA, nullptr);
    k_mgemm<64, false><<<(NN + 63) / 64, 256, 0, stream>>>(aggA, wp1, b1, nullptr,
                                                           nullptr, h1, nullptr,
                                                           sums, sumsq);

    // 3. BN finalize + layer-2 weight prep (scale/shift folded into W2/sv)
    k_bn_finalize<<<1, 128, 0, stream>>>(sums, sumsq, gamma, beta, scale, shift);
    k_pack<true><<<64, 256, 0, stream>>>(W2, scale, wp2, 128);
    k_sv<<<1, 128, 0, stream>>>(W2, shift, sv);

    // 4. layer 2: aggregate h1 (128) -> aggB f16 + sumcoef, MFMA GEMM -> d_out f32
    k_agg<128, true><<<NN / 8, 256, 0, stream>>>(h1, rows, start, cnt, dis,
                                                 aggB, sumcoef);
    k_mgemm<128, true><<<(NN + 63) / 64, 256, 0, stream>>>(aggB, wp2, b2, sv,
                                                           sumcoef, nullptr, out,
                                                           nullptr, nullptr);
}

// Round 6
// 238.696 us; speedup vs baseline: 23.6741x; 1.0045x over previous
//
#include <hip/hip_runtime.h>

#define NN 100000
#define BN_EPS 1e-5f
#define NB 391          // buckets = ceil(NN/256), bucket b owns cols [b*256, b*256+256)
#define CAP 5120        // per-bucket edge capacity
#define TILE 4096       // edges per k_bin block

#define CVT_BLKS 6250   // NN*16 float4s / 256
#define ZERO_BLKS 33    // 8192 bcur + 256 stats = 8448 ints
#define PACK1_BLKS 32   // 64*128 / 256

typedef __attribute__((ext_vector_type(4))) _Float16 half4;
typedef __attribute__((ext_vector_type(8))) _Float16 half8;
typedef __attribute__((ext_vector_type(4))) float f32x4;

// ---------------- pass 1: bin edges by col>>8, bucket-sorted coalesced writes ----------------

__global__ __launch_bounds__(256) void k_bin(const int* __restrict__ row,
                                             const int* __restrict__ col,
                                             int* __restrict__ bcur,   // NB counters, stride 16
                                             int* __restrict__ ebuf,   // NB*CAP packed edges
                                             int E) {
    __shared__ int hist[512];
    __shared__ int excl[512];
    __shared__ int cur[512];
    __shared__ int gbase[512];
    __shared__ int sc[256];
    __shared__ int staged[TILE];
    __shared__ unsigned short bkt[TILE];
    const int t = threadIdx.x;
    const int base = blockIdx.x * TILE;
    const int nE = min(TILE, E - base);

    hist[t] = 0; hist[t + 256] = 0;
    cur[t] = 0;  cur[t + 256] = 0;
    __syncthreads();

    int er[16], ec[16];
    #pragma unroll
    for (int k = 0; k < 16; ++k) {
        int idx = base + k * 256 + t;
        if (idx < E) {
            er[k] = row[idx];
            ec[k] = col[idx];
            atomicAdd(&hist[ec[k] >> 8], 1);
        } else {
            ec[k] = -1;
        }
    }
    __syncthreads();

    int p = hist[2 * t] + hist[2 * t + 1];
    sc[t] = p;
    __syncthreads();
    for (int off = 1; off < 256; off <<= 1) {
        int add = (t >= off) ? sc[t - off] : 0;
        __syncthreads();
        sc[t] += add;
        __syncthreads();
    }
    int P = sc[t];
    excl[2 * t]     = P - p;
    excl[2 * t + 1] = P - p + hist[2 * t];
    __syncthreads();

    for (int b = t; b < NB; b += 256) {
        int h = hist[b];
        gbase[b] = h ? atomicAdd(&bcur[b * 16], h) : 0;
    }

    #pragma unroll
    for (int k = 0; k < 16; ++k) {
        int c = ec[k];
        if (c < 0) continue;
        int b = c >> 8;
        int slot = excl[b] + atomicAdd(&cur[b], 1);
        staged[slot] = (er[k] << 8) | (c & 255);
        bkt[slot] = (unsigned short)b;
    }
    __syncthreads();

    for (int i = t; i < nE; i += 256) {
        int b = bkt[i];
        int off = gbase[b] + (i - excl[b]);
        if (off < CAP) ebuf[b * CAP + off] = staged[i];
    }
}

// ---------------- pass 2: per-bucket CSR finalize ----------------

__global__ __launch_bounds__(256) void k_csr(const int* __restrict__ bcur,
                                             const int* __restrict__ ebuf,
                                             int* __restrict__ rows,
                                             int* __restrict__ start,
                                             int* __restrict__ cnt,
                                             float* __restrict__ dis) {
    __shared__ int hist[256];
    __shared__ int lstart[256];
    __shared__ int cur[256];
    __shared__ int sc[256];
    const int b = blockIdx.x;
    const int t = threadIdx.x;
    const int fill = min(bcur[b * 16], CAP);

    hist[t] = 0; cur[t] = 0;
    __syncthreads();

    int er[CAP / 256];
    #pragma unroll
    for (int k = 0; k < CAP / 256; ++k) {
        int i = k * 256 + t;
        if (i < fill) {
            er[k] = ebuf[b * CAP + i];
            atomicAdd(&hist[er[k] & 255], 1);
        }
    }
    __syncthreads();

    int v = hist[t];
    sc[t] = v;
    __syncthreads();
    for (int off = 1; off < 256; off <<= 1) {
        int add = (t >= off) ? sc[t - off] : 0;
        __syncthreads();
        sc[t] += add;
        __syncthreads();
    }
    lstart[t] = sc[t] - v;

    const int node = b * 256 + t;
    if (node < NN) {
        start[node] = b * CAP + lstart[t];
        cnt[node] = v;
        dis[node] = rsqrtf((float)(v + 1));
    }
    __syncthreads();

    #pragma unroll
    for (int k = 0; k < CAP / 256; ++k) {
        int i = k * 256 + t;
        if (i < fill) {
            int lc = er[k] & 255;
            int lpos = atomicAdd(&cur[lc], 1);
            rows[b * CAP + lstart[lc] + lpos] = er[k] >> 8;
        }
    }
}

// ---------------- fused prep: x->f16 | zero counters/stats | pack W1 ----------------
// wp flat idx i = ((kt*8 + nt)*64 + l)*8 + j  ->  W[kt*32 + (l>>4)*8 + j][nt*16 + (l&15)]

__global__ __launch_bounds__(256) void k_prep(const float* __restrict__ x,
                                              _Float16* __restrict__ xh,
                                              int* __restrict__ bcur,
                                              float* __restrict__ stats,   // sums+sumsq (256)
                                              const float* __restrict__ W1,
                                              _Float16* __restrict__ wp1) {
    const int b = blockIdx.x;
    const int t = threadIdx.x;
    if (b < CVT_BLKS) {
        int i = b * 256 + t;                 // float4 index, NN*16 total
        float4 v = reinterpret_cast<const float4*>(x)[i];
        half4 o;
        o.x = (_Float16)v.x; o.y = (_Float16)v.y;
        o.z = (_Float16)v.z; o.w = (_Float16)v.w;
        reinterpret_cast<half4*>(xh)[i] = o;
    } else if (b < CVT_BLKS + ZERO_BLKS) {
        int i = (b - CVT_BLKS) * 256 + t;
        if (i < 8192) bcur[i] = 0;
        else if (i < 8448) stats[i - 8192] = 0.f;
    } else {
        int i = (b - CVT_BLKS - ZERO_BLKS) * 256 + t;   // < 8192
        int j = i & 7, l = (i >> 3) & 63, nt = (i >> 9) & 7, kt = i >> 12;
        int k = kt * 32 + ((l >> 4) << 3) + j;
        int n = nt * 16 + (l & 15);
        wp1[i] = (_Float16)W1[k * 128 + n];
    }
}

// ---------------- fused layer-2 prep: BN finalize (redundant) + pack scaled W2 + sv ----------------

__global__ __launch_bounds__(256) void k_l2prep(const float* __restrict__ sums,
                                                const float* __restrict__ sumsq,
                                                const float* __restrict__ gamma,
                                                const float* __restrict__ beta,
                                                const float* __restrict__ W2,
                                                _Float16* __restrict__ wp2,
                                                float* __restrict__ sv) {
    __shared__ float scl[128];
    __shared__ float shf[128];
    const int b = blockIdx.x;
    const int t = threadIdx.x;
    if (t < 128) {
        const float n = (float)NN;
        float mean = sums[t] / n;
        float var = sumsq[t] / n - mean * mean;
        float sc = gamma[t] * rsqrtf(var + BN_EPS);
        scl[t] = sc;
        shf[t] = beta[t] - mean * sc;
    }
    __syncthreads();
    if (b < 64) {
        int i = b * 256 + t;                 // < 16384
        int j = i & 7, l = (i >> 3) & 63, nt = (i >> 9) & 7, kt = i >> 12;
        int k = kt * 32 + ((l >> 4) << 3) + j;
        int n = nt * 16 + (l & 15);
        wp2[i] = (_Float16)(W2[k * 128 + n] * scl[k]);
    } else if (t < 128) {
        float s = 0.f;
        for (int k = 0; k < 128; ++k) s += shf[k] * W2[k * 128 + t];
        sv[t] = s;
    }
}

// ---------------- pull aggregation (half8/lane, 8-deep unrolled gather) ----------------

template<int F, bool SUMC>
__global__ __launch_bounds__(256) void k_agg(const _Float16* __restrict__ xh,
                                             const int* __restrict__ rows,
                                             const int* __restrict__ start,
                                             const int* __restrict__ cnt,
                                             const float* __restrict__ dis,
                                             _Float16* __restrict__ agg,
                                             float* __restrict__ sumcoef) {
    constexpr int L = F / 8;                 // lanes per node (half8 each)
    const int t = threadIdx.x;
    const int g = t / L;
    const int fid = t % L;
    const int n = blockIdx.x * (256 / L) + g;
    if (n >= NN) return;
    const int s = start[n];
    const int c = cnt[n];
    const float dn = dis[n];
    const half8* X8 = reinterpret_cast<const half8*>(xh);
    half8 hv = X8[n * L + fid];
    const float dn2 = dn * dn;
    float acc[8];
    #pragma unroll
    for (int j = 0; j < 8; ++j) acc[j] = dn2 * (float)hv[j];
    float sd = 0.f;
    const int* rp = rows + s;
    int k = 0;
    for (; k + 8 <= c; k += 8) {
        int r[8];
        #pragma unroll
        for (int u = 0; u < 8; ++u) r[u] = rp[k + u];
        float d[8];
        #pragma unroll
        for (int u = 0; u < 8; ++u) d[u] = dis[r[u]];
        half8 v[8];
        #pragma unroll
        for (int u = 0; u < 8; ++u) v[u] = X8[r[u] * L + fid];
        #pragma unroll
        for (int u = 0; u < 8; ++u) {
            const float coef = d[u] * dn;
            #pragma unroll
            for (int j = 0; j < 8; ++j)
                acc[j] = fmaf((float)v[u][j], coef, acc[j]);
            sd += d[u];
        }
    }
    for (; k < c; ++k) {
        int r = rp[k];
        float dr = dis[r];
        half8 v = X8[r * L + fid];
        const float coef = dr * dn;
        #pragma unroll
        for (int j = 0; j < 8; ++j)
            acc[j] = fmaf((float)v[j], coef, acc[j]);
        sd += dr;
    }
    half8 o;
    #pragma unroll
    for (int j = 0; j < 8; ++j) o[j] = (_Float16)acc[j];
    reinterpret_cast<half8*>(agg)[n * L + fid] = o;
    if (SUMC && fid == 0) sumcoef[n] = dn * sd + dn2;
}

// ---------------- MFMA GEMM: [NN,K] f16 @ packed W -> 128 cols ----------------

template<int K, bool L2E>
__global__ __launch_bounds__(256) void k_mgemm(const _Float16* __restrict__ A,
                                               const _Float16* __restrict__ Wp,
                                               const float* __restrict__ bias,
                                               const float* __restrict__ sv,
                                               const float* __restrict__ sumcoef,
                                               _Float16* __restrict__ out16,
                                               float* __restrict__ out32,
                                               float* __restrict__ sums,
                                               float* __restrict__ sumsq) {
    const int t = threadIdx.x;
    const int wv = t >> 6;
    const int ln = t & 63;
    const int cgrp = ln >> 4;
    const int ncol = ln & 15;
    const int r0 = blockIdx.x * 64 + wv * 16;
    const int arow = min(r0 + ncol, NN - 1);

    f32x4 acc[8];
    #pragma unroll
    for (int nt = 0; nt < 8; ++nt) acc[nt] = {0.f, 0.f, 0.f, 0.f};

    const half8* Ap = reinterpret_cast<const half8*>(A + arow * K + cgrp * 8);
    const half8* Bp = reinterpret_cast<const half8*>(Wp);

    #pragma unroll
    for (int kt = 0; kt < K / 32; ++kt) {
        half8 a = Ap[kt * 4];
        #pragma unroll
        for (int nt = 0; nt < 8; ++nt) {
            half8 b = Bp[(kt * 8 + nt) * 64 + ln];
            acc[nt] = __builtin_amdgcn_mfma_f32_16x16x32_f16(a, b, acc[nt], 0, 0, 0);
        }
    }

    if constexpr (!L2E) {
        __shared__ float ls[4][128];
        __shared__ float ls2[4][128];
        #pragma unroll
        for (int nt = 0; nt < 8; ++nt) {
            const int n = nt * 16 + ncol;
            const float bn = bias[n];
            float s = 0.f, s2 = 0.f;
            #pragma unroll
            for (int j = 0; j < 4; ++j) {
                int gr = r0 + cgrp * 4 + j;
                float v = acc[nt][j] + bn;
                if (gr < NN) {
                    out16[gr * 128 + n] = (_Float16)v;
                    s += v;
                    s2 += v * v;
                }
            }
            s  += __shfl_xor(s, 16);  s  += __shfl_xor(s, 32);
            s2 += __shfl_xor(s2, 16); s2 += __shfl_xor(s2, 32);
            if (ln < 16) { ls[wv][n] = s; ls2[wv][n] = s2; }
        }
        __syncthreads();
        if (t < 128) {
            atomicAdd(&sums[t], ls[0][t] + ls[1][t] + ls[2][t] + ls[3][t]);
        } else {
            int u = t - 128;
            atomicAdd(&sumsq[u], ls2[0][u] + ls2[1][u] + ls2[2][u] + ls2[3][u]);
        }
    } else {
        float scj[4];
        #pragma unroll
        for (int j = 0; j < 4; ++j) scj[j] = sumcoef[min(r0 + cgrp * 4 + j, NN - 1)];
        #pragma unroll
        for (int nt = 0; nt < 8; ++nt) {
            const int n = nt * 16 + ncol;
            const float svn = sv[n];
            const float bn = bias[n];
            #pragma unroll
            for (int j = 0; j < 4; ++j) {
                int gr = r0 + cgrp * 4 + j;
                if (gr < NN) out32[gr * 128 + n] = acc[nt][j] + scj[j] * svn + bn;
            }
        }
    }
}

// ---------------- launch ----------------

extern "C" void kernel_launch(void* const* d_in, const int* in_sizes, int n_in,
                              void* d_out, int out_size, void* d_ws, size_t ws_size,
                              hipStream_t stream) {
    const float* x     = (const float*)d_in[0];   // [NN, 64]
    const int*   ei    = (const int*)d_in[1];     // [2, E]
    const float* W1    = (const float*)d_in[2];
    const float* b1    = (const float*)d_in[3];
    const float* gamma = (const float*)d_in[4];
    const float* beta  = (const float*)d_in[5];
    const float* W2    = (const float*)d_in[6];
    const float* b2    = (const float*)d_in[7];
    float* out = (float*)d_out;                   // [NN, 128]

    const int E = in_sizes[1] / 2;
    const int* row = ei;
    const int* col = ei + E;

    // workspace layout (4-byte units)
    int*   bcur    = (int*)d_ws;                      // 8192
    int*   cnt     = bcur + 8192;                     // 102400
    int*   start   = cnt + 102400;                    // 102400
    float* dis     = (float*)(start + 102400);        // 102400
    float* sums    = dis + 102400;                    // 128
    float* sumsq   = sums + 128;                      // 128 (contiguous with sums)
    float* sv      = sumsq + 128;                     // 128 (region padded to 1024)
    float* sumcoef = sums + 1024;                     // 102400
    _Float16* wp1  = (_Float16*)(sumcoef + 102400);   // 8192 halves
    _Float16* wp2  = wp1 + 8192;                      // 16384 halves
    int*   rows    = (int*)(wp2 + 16384);             // NB*CAP
    int*   Rbase   = rows + NB * CAP;                 // reuse region
    _Float16* xh   = (_Float16*)Rbase;                //   pass A: NN*64 f16
    int*   ebuf    = Rbase + 3276800;                 //   pass A: NB*CAP ints
    _Float16* aggB = (_Float16*)Rbase;                //   pass B: NN*128 f16
    _Float16* h1   = (_Float16*)(Rbase + 6400000);    // NN*128 f16
    _Float16* aggA = (_Float16*)d_out;                // NN*64 f16 parked in d_out

    // 1. prep (cvt + zero + pack W1), CSR build
    k_prep<<<CVT_BLKS + ZERO_BLKS + PACK1_BLKS, 256, 0, stream>>>(x, xh, bcur,
                                                                  sums, W1, wp1);
    k_bin<<<(E + TILE - 1) / TILE, 256, 0, stream>>>(row, col, bcur, ebuf, E);
    k_csr<<<NB, 256, 0, stream>>>(bcur, ebuf, rows, start, cnt, dis);

    // 2. layer 1: aggregate xh (64) -> aggA f16, MFMA GEMM -> h1 f16 (+ fused BN stats)
    k_agg<64, false><<<NN / 32, 256, 0, stream>>>(xh, rows, start, cnt, dis,
                                                  aggA, nullptr);
    k_mgemm<64, false><<<(NN + 63) / 64, 256, 0, stream>>>(aggA, wp1, b1, nullptr,
                                                           nullptr, h1, nullptr,
                                                           sums, sumsq);

    // 3. fused BN finalize + W2 pack (scaled) + sv
    k_l2prep<<<65, 256, 0, stream>>>(sums, sumsq, gamma, beta, W2, wp2, sv);

    // 4. layer 2: aggregate h1 (128) -> aggB f16 + sumcoef, MFMA GEMM -> d_out f32
    k_agg<128, true><<<NN / 16, 256, 0, stream>>>(h1, rows, start, cnt, dis,
                                                  aggB, sumcoef);
    k_mgemm<128, true><<<(NN + 63) / 64, 256, 0, stream>>>(aggB, wp2, b2, sv,
                                                           sumcoef, nullptr, out,
                                                           nullptr, nullptr);
}